// Round 1
// baseline (1856.862 us; speedup 1.0000x reference)
//
#include <hip/hip_runtime.h>
#include <math.h>

#define RNK 10
#define NG  55          // packed lower-triangular 10x10
#define TPB 256
#define PCH 32          // row-chunks per pass kernel (grid.y)
#define ITILE 16        // rows per block in final GEMM

__device__ __forceinline__ constexpr int tri(int a, int b) { return a*(a+1)/2 + b; }

// ---------------- init kernels ----------------

__global__ void alpha_kernel(const float* __restrict__ cptr, float* __restrict__ alpha) {
    float c  = *cptr;
    float A  = erff(c * 0.70710678118654752f);              // chi2_cdf(c^2, 1)
    float B  = c * 0.79788456080286536f * expf(-0.5f*c*c);  // correction term
    // chi2_cdf(c^2,3) = A - B
    *alpha = 0.5f*c*c*(1.0f - A) + 0.5f*(A - B);
}

__global__ void init_uv_kernel(const float* __restrict__ Uin, const float* __restrict__ Vin,
                               float* __restrict__ Ut, float* __restrict__ Vc, int m, int n) {
    int idx = blockIdx.x * blockDim.x + threadIdx.x;
    if (idx < RNK * m) {
        int k = idx / m, i = idx - k*m;
        Ut[idx] = Uin[i*RNK + k];          // U [m,r] -> Ut [r,m]
    }
    if (idx < RNK * n) Vc[idx] = Vin[idx]; // V already [r,n]
}

__global__ void zero_kernel(float* __restrict__ p, int nelem) {
    int idx = blockIdx.x * blockDim.x + threadIdx.x;
    if (idx < nelem) p[idx] = 0.0f;
}

// X [m,n] -> XT [n,m], 32x32 LDS tile
__global__ void transpose_kernel(const float* __restrict__ X, float* __restrict__ XT,
                                 int m, int n) {
    __shared__ float tile[32][33];
    int bx = blockIdx.x * 32;  // col base in X
    int by = blockIdx.y * 32;  // row base in X
    int tx = threadIdx.x, ty = threadIdx.y;  // block (32,8)
    #pragma unroll
    for (int dy = 0; dy < 32; dy += 8)
        tile[ty+dy][tx] = X[(size_t)(by+ty+dy)*n + bx + tx];
    __syncthreads();
    #pragma unroll
    for (int dy = 0; dy < 32; dy += 8)
        XT[(size_t)(bx+ty+dy)*m + by + tx] = tile[tx][ty+dy];
}

// ---------------- hubreg kernels ----------------
// Layouts: Y [p,q] row-major (regression index j is the fast axis -> coalesced),
//          Dm [r,p]  (D row i = Dm[k*p+i], wave-uniform broadcast loads),
//          Bm [r,q]  (beta_j[k] = Bm[k*q+j], coalesced per-thread).

// Gram: Gbuf[tri(a,b)*q + j] += mask(i,j) * D[i,a]*D[i,b];  Gbuf[NG*q+j] += mask (nobs)
__global__ void g_kernel(const float* __restrict__ Y, const float* __restrict__ Dm,
                         float* __restrict__ Gbuf, int q, int p, int rows) {
    int j  = blockIdx.x * TPB + threadIdx.x;
    int i0 = blockIdx.y * rows, i1 = i0 + rows;
    float acc[NG];
    #pragma unroll
    for (int k = 0; k < NG; ++k) acc[k] = 0.0f;
    float cnt = 0.0f;
    for (int i = i0; i < i1; ++i) {
        float d[RNK];
        #pragma unroll
        for (int k = 0; k < RNK; ++k) d[k] = Dm[k*p + i];
        float y   = Y[(size_t)i*q + j];
        float msk = (y != 0.0f) ? 1.0f : 0.0f;
        cnt += msk;
        float dm[RNK];
        #pragma unroll
        for (int k = 0; k < RNK; ++k) dm[k] = msk * d[k];
        #pragma unroll
        for (int a = 0; a < RNK; ++a)
            #pragma unroll
            for (int b = 0; b <= a; ++b)
                acc[tri(a,b)] = fmaf(dm[a], d[b], acc[tri(a,b)]);
    }
    #pragma unroll
    for (int k = 0; k < NG; ++k) atomicAdd(&Gbuf[k*q + j], acc[k]);
    atomicAdd(&Gbuf[NG*q + j], cnt);
}

// Per-regression Cholesky (packed, in registers) + sigma/tau init
__global__ void chol_kernel(float* __restrict__ Gbuf, float* __restrict__ sigma,
                            float* __restrict__ tauacc, const float* __restrict__ sigma0,
                            int q) {
    int j = blockIdx.x * TPB + threadIdx.x;
    if (j >= q) return;
    float g[NG];
    #pragma unroll
    for (int k = 0; k < NG; ++k) g[k] = Gbuf[k*q + j];
    #pragma unroll
    for (int a = 0; a < RNK; ++a) {
        #pragma unroll
        for (int b = 0; b < a; ++b) {
            float s = g[tri(a,b)];
            #pragma unroll
            for (int k = 0; k < b; ++k) s -= g[tri(a,k)] * g[tri(b,k)];
            g[tri(a,b)] = s / g[tri(b,b)];
        }
        float s = g[tri(a,a)];
        #pragma unroll
        for (int k = 0; k < a; ++k) s -= g[tri(a,k)] * g[tri(a,k)];
        g[tri(a,a)] = sqrtf(s);
    }
    #pragma unroll
    for (int k = 0; k < NG; ++k) Gbuf[k*q + j] = g[k];
    sigma[j]  = *sigma0;
    tauacc[j] = 0.0f;
}

// pass1: accumulate sum of (psi*sigma)^2 per regression
__global__ void pass1_kernel(const float* __restrict__ Y, const float* __restrict__ Dm,
                             const float* __restrict__ Bm, const float* __restrict__ sigma,
                             const float* __restrict__ cptr, float* __restrict__ tauacc,
                             int q, int p, int rows) {
    int j  = blockIdx.x * TPB + threadIdx.x;
    int i0 = blockIdx.y * rows, i1 = i0 + rows;
    float b[RNK];
    #pragma unroll
    for (int k = 0; k < RNK; ++k) b[k] = Bm[k*q + j];
    float csg = (*cptr) * sigma[j];
    float acc = 0.0f;
    for (int i = i0; i < i1; ++i) {
        float y = Y[(size_t)i*q + j];
        float dot = 0.0f;
        #pragma unroll
        for (int k = 0; k < RNK; ++k) dot = fmaf(Dm[k*p + i], b[k], dot);
        float r = y - dot;
        r = (y != 0.0f) ? r : 0.0f;
        r = fminf(fmaxf(r, -csg), csg);   // psi(R/sig)*sig
        acc = fmaf(r, r, acc);
    }
    atomicAdd(&tauacc[j], acc);
}

// sigma update:  tau = sqrt(sum(psi^2)) / sqrt(2*nobs*alpha);  sigma *= tau^lamda
// we accumulated (psi*sig)^2 so divide by sig. Also zero rhs for pass2.
__global__ void sigma_kernel(const float* __restrict__ tauacc, const float* __restrict__ Gbuf,
                             float* __restrict__ sigma, const float* __restrict__ alphap,
                             const float* __restrict__ lamdap, float* __restrict__ rhs, int q) {
    int j = blockIdx.x * TPB + threadIdx.x;
    if (j >= q) return;
    float nobs = Gbuf[NG*q + j];
    float sg   = sigma[j];
    float tau  = sqrtf(tauacc[j] / (2.0f * nobs * (*alphap))) / sg;
    sigma[j]   = sg * powf(tau, *lamdap);
    #pragma unroll
    for (int k = 0; k < RNK; ++k) rhs[k*q + j] = 0.0f;
}

// pass2: rhs[k][j] += D[i,k] * psi2*sigma   (psi2*sigma = clamp(resid, +-c*sigma_new))
__global__ void pass2_kernel(const float* __restrict__ Y, const float* __restrict__ Dm,
                             const float* __restrict__ Bm, const float* __restrict__ sigma,
                             const float* __restrict__ cptr, float* __restrict__ rhs,
                             int q, int p, int rows) {
    int j  = blockIdx.x * TPB + threadIdx.x;
    int i0 = blockIdx.y * rows, i1 = i0 + rows;
    float b[RNK];
    #pragma unroll
    for (int k = 0; k < RNK; ++k) b[k] = Bm[k*q + j];
    float csg = (*cptr) * sigma[j];
    float acc[RNK];
    #pragma unroll
    for (int k = 0; k < RNK; ++k) acc[k] = 0.0f;
    for (int i = i0; i < i1; ++i) {
        float y = Y[(size_t)i*q + j];
        float d[RNK];
        #pragma unroll
        for (int k = 0; k < RNK; ++k) d[k] = Dm[k*p + i];
        float dot = 0.0f;
        #pragma unroll
        for (int k = 0; k < RNK; ++k) dot = fmaf(d[k], b[k], dot);
        float r = y - dot;
        r = (y != 0.0f) ? r : 0.0f;
        r = fminf(fmaxf(r, -csg), csg);   // psi2 * sigma
        #pragma unroll
        for (int k = 0; k < RNK; ++k) acc[k] = fmaf(d[k], r, acc[k]);
    }
    #pragma unroll
    for (int k = 0; k < RNK; ++k) atomicAdd(&rhs[k*q + j], acc[k]);
}

// solve G delta = rhs via stored Cholesky, beta += mu*delta; zero tauacc for next iter
__global__ void update_kernel(const float* __restrict__ Gbuf, const float* __restrict__ rhs,
                              float* __restrict__ Bm, const float* __restrict__ mup,
                              float* __restrict__ tauacc, int q) {
    int j = blockIdx.x * TPB + threadIdx.x;
    if (j >= q) return;
    float L[NG];
    #pragma unroll
    for (int k = 0; k < NG; ++k) L[k] = Gbuf[k*q + j];
    float x[RNK];
    #pragma unroll
    for (int k = 0; k < RNK; ++k) x[k] = rhs[k*q + j];
    #pragma unroll
    for (int a = 0; a < RNK; ++a) {          // forward: L y = rhs
        float s = x[a];
        #pragma unroll
        for (int k = 0; k < a; ++k) s -= L[tri(a,k)] * x[k];
        x[a] = s / L[tri(a,a)];
    }
    #pragma unroll
    for (int a = RNK-1; a >= 0; --a) {       // backward: L^T d = y
        float s = x[a];
        #pragma unroll
        for (int k = a+1; k < RNK; ++k) s -= L[tri(k,a)] * x[k];
        x[a] = s / L[tri(a,a)];
    }
    float mu = *mup;
    #pragma unroll
    for (int k = 0; k < RNK; ++k) Bm[k*q + j] += mu * x[k];
    tauacc[j] = 0.0f;
}

// final: out[i*n+j] = sum_k Ut[k*m+i] * Vc[k*n+j]
__global__ void gemm_kernel(const float* __restrict__ Ut, const float* __restrict__ Vc,
                            float* __restrict__ out, int m, int n) {
    int j  = blockIdx.x * TPB + threadIdx.x;
    int i0 = blockIdx.y * ITILE;
    float v[RNK];
    #pragma unroll
    for (int k = 0; k < RNK; ++k) v[k] = Vc[k*n + j];
    for (int i = i0; i < i0 + ITILE; ++i) {
        float acc = 0.0f;
        #pragma unroll
        for (int k = 0; k < RNK; ++k) acc = fmaf(Ut[k*m + i], v[k], acc);
        out[(size_t)i*n + j] = acc;
    }
}

// ---------------- host side ----------------

namespace {
struct Scratch {
    float *Ut, *Vc, *Gbuf, *rhs, *sigma, *tauacc, *alpha;
};

static void hubreg(const float* Y, const float* Dm, float* Bm, int q, int p,
                   const float* c, const float* lamda, const float* mu, const float* sigma0,
                   const Scratch& s, hipStream_t stream) {
    int rows = p / PCH;
    dim3 gpass(q / TPB, PCH);
    dim3 gj((q + TPB - 1) / TPB);

    zero_kernel<<<((NG+1)*q + TPB - 1) / TPB, TPB, 0, stream>>>(s.Gbuf, (NG+1)*q);
    g_kernel<<<gpass, TPB, 0, stream>>>(Y, Dm, s.Gbuf, q, p, rows);
    chol_kernel<<<gj, TPB, 0, stream>>>(s.Gbuf, s.sigma, s.tauacc, sigma0, q);
    for (int it = 0; it < 2; ++it) {
        pass1_kernel<<<gpass, TPB, 0, stream>>>(Y, Dm, Bm, s.sigma, c, s.tauacc, q, p, rows);
        sigma_kernel<<<gj, TPB, 0, stream>>>(s.tauacc, s.Gbuf, s.sigma, s.alpha, lamda, s.rhs, q);
        pass2_kernel<<<gpass, TPB, 0, stream>>>(Y, Dm, Bm, s.sigma, c, s.rhs, q, p, rows);
        update_kernel<<<gj, TPB, 0, stream>>>(s.Gbuf, s.rhs, Bm, mu, s.tauacc, q);
    }
}
} // namespace

extern "C" void kernel_launch(void* const* d_in, const int* in_sizes, int n_in,
                              void* d_out, int out_size, void* d_ws, size_t ws_size,
                              hipStream_t stream) {
    const float* Uin    = (const float*)d_in[0];
    const float* Vin    = (const float*)d_in[1];
    const float* X      = (const float*)d_in[2];
    const float* c      = (const float*)d_in[3];
    const float* lamda  = (const float*)d_in[4];
    const float* mu     = (const float*)d_in[5];
    const float* sigma0 = (const float*)d_in[6];
    float* out = (float*)d_out;

    const int m = in_sizes[0] / RNK;   // 4096
    const int n = in_sizes[1] / RNK;   // 4096
    const int qmax = (m > n) ? m : n;

    // workspace carve-up (floats), 256B-aligned regions
    float* w = (float*)d_ws;
    auto align64 = [](size_t x) { return (x + 63) & ~(size_t)63; };
    size_t off = 0;
    Scratch s;
    s.Ut     = w + off; off = align64(off + (size_t)RNK * m);
    s.Vc     = w + off; off = align64(off + (size_t)RNK * n);
    s.Gbuf   = w + off; off = align64(off + (size_t)(NG + 1) * qmax);
    s.rhs    = w + off; off = align64(off + (size_t)RNK * qmax);
    s.sigma  = w + off; off = align64(off + (size_t)qmax);
    s.tauacc = w + off; off = align64(off + (size_t)qmax);
    s.alpha  = w + off; off = align64(off + 64);
    (void)ws_size; (void)n_in; (void)out_size;

    alpha_kernel<<<1, 1, 0, stream>>>(c, s.alpha);
    {
        int tot = RNK * qmax;
        init_uv_kernel<<<(tot + TPB - 1) / TPB, TPB, 0, stream>>>(Uin, Vin, s.Ut, s.Vc, m, n);
    }
    // X [m,n] -> XT [n,m] staged in d_out (dead until final GEMM overwrites it)
    transpose_kernel<<<dim3(n / 32, m / 32), dim3(32, 8), 0, stream>>>(X, out, m, n);

    for (int layer = 0; layer < 3; ++layer) {
        // V-step: regressions = columns of X (q=n, p=m), D = U rows, beta = V cols
        hubreg(X,   s.Ut, s.Vc, n, m, c, lamda, mu, sigma0, s, stream);
        // U-step: regressions = rows of X (q=m, p=n), Y = XT, D = V cols, beta = U rows
        hubreg(out, s.Vc, s.Ut, m, n, c, lamda, mu, sigma0, s, stream);
    }

    gemm_kernel<<<dim3(n / TPB, m / ITILE), TPB, 0, stream>>>(s.Ut, s.Vc, out, m, n);
}

// Round 2
// 1639.652 us; speedup vs baseline: 1.1325x; 1.1325x over previous
//
#include <hip/hip_runtime.h>
#include <math.h>

#define RNK 10
#define NG  55          // packed lower-triangular 10x10
#define TPB 256
#define PCH_G 64        // row-chunks for fused gram+pass1 (grid.y)
#define PCH_P 128       // row-chunks for pass1/pass2 (grid.y)
#define ITILE 16        // rows per block in final GEMM

__device__ __forceinline__ constexpr int tri(int a, int b) { return a*(a+1)/2 + b; }

// ---------------- init ----------------
// zero Gbuf/tauacc, transpose U -> Ut [r,m], copy V -> Vc [r,n], compute alpha
__global__ void init_kernel(const float* __restrict__ Uin, const float* __restrict__ Vin,
                            const float* __restrict__ cptr,
                            float* __restrict__ Ut, float* __restrict__ Vc,
                            float* __restrict__ Gbuf, float* __restrict__ tauacc,
                            float* __restrict__ alpha, int m, int n, int qmax) {
    int idx = blockIdx.x * TPB + threadIdx.x;
    if (idx == 0) {
        float c  = *cptr;
        float A  = erff(c * 0.70710678118654752f);              // chi2_cdf(c^2, 1)
        float B  = c * 0.79788456080286536f * expf(-0.5f*c*c);
        *alpha = 0.5f*c*c*(1.0f - A) + 0.5f*(A - B);            // chi2_cdf(c^2,3)=A-B
    }
    if (idx < RNK * m) { int k = idx / m, i = idx - k*m; Ut[idx] = Uin[i*RNK + k]; }
    if (idx < RNK * n) Vc[idx] = Vin[idx];
    if (idx < (NG + 1) * qmax) Gbuf[idx] = 0.0f;
    if (idx < qmax) tauacc[idx] = 0.0f;
}

// X [m,n] -> XT [n,m], 32x32 LDS tile
__global__ void transpose_kernel(const float* __restrict__ X, float* __restrict__ XT,
                                 int m, int n) {
    __shared__ float tile[32][33];
    int bx = blockIdx.x * 32, by = blockIdx.y * 32;
    int tx = threadIdx.x, ty = threadIdx.y;  // block (32,8)
    #pragma unroll
    for (int dy = 0; dy < 32; dy += 8)
        tile[ty+dy][tx] = X[(size_t)(by+ty+dy)*n + bx + tx];
    __syncthreads();
    #pragma unroll
    for (int dy = 0; dy < 32; dy += 8)
        XT[(size_t)(bx+ty+dy)*m + by + tx] = tile[tx][ty+dy];
}

// ---------------- hubreg kernels ----------------
// Layouts: Y [p,q] (regression j fast axis), Dm [r,p] (wave-uniform rows),
//          Bm [r,q] (coalesced per-thread beta).

// Fused Gram + pass1(it=0): pass1 at it=0 uses initial beta and scalar sigma0,
// so it shares the Y sweep with the Gram accumulation.
__global__ void gp1_kernel(const float* __restrict__ Y, const float* __restrict__ Dm,
                           const float* __restrict__ Bm, const float* __restrict__ cptr,
                           const float* __restrict__ sigma0,
                           float* __restrict__ Gbuf, float* __restrict__ tauacc,
                           int q, int p, int rows) {
    int j  = blockIdx.x * TPB + threadIdx.x;
    int i0 = blockIdx.y * rows, i1 = i0 + rows;
    float b[RNK];
    #pragma unroll
    for (int k = 0; k < RNK; ++k) b[k] = Bm[k*q + j];
    float csg = (*cptr) * (*sigma0);
    float acc[NG];
    #pragma unroll
    for (int k = 0; k < NG; ++k) acc[k] = 0.0f;
    float cnt = 0.0f, p1 = 0.0f;
    float y = Y[(size_t)i0*q + j];
    for (int i = i0; i < i1; ++i) {
        float ynxt = (i + 1 < i1) ? Y[(size_t)(i+1)*q + j] : 0.0f;   // prefetch
        float d[RNK];
        #pragma unroll
        for (int k = 0; k < RNK; ++k) d[k] = Dm[k*p + i];
        float msk = (y != 0.0f) ? 1.0f : 0.0f;
        cnt += msk;
        float dot = 0.0f;
        #pragma unroll
        for (int k = 0; k < RNK; ++k) dot = fmaf(d[k], b[k], dot);
        float r = y - dot;
        r = (y != 0.0f) ? r : 0.0f;
        r = fminf(fmaxf(r, -csg), csg);          // psi(R/sig0)*sig0
        p1 = fmaf(r, r, p1);
        float dm[RNK];
        #pragma unroll
        for (int k = 0; k < RNK; ++k) dm[k] = msk * d[k];
        #pragma unroll
        for (int a = 0; a < RNK; ++a)
            #pragma unroll
            for (int bb = 0; bb <= a; ++bb)
                acc[tri(a,bb)] = fmaf(dm[a], d[bb], acc[tri(a,bb)]);
        y = ynxt;
    }
    #pragma unroll
    for (int k = 0; k < NG; ++k) atomicAdd(&Gbuf[k*q + j], acc[k]);
    atomicAdd(&Gbuf[NG*q + j], cnt);
    atomicAdd(&tauacc[j], p1);
}

// Fused Cholesky + sigma-update (it=0, sigma_old = sigma0) + rhs zeroing
__global__ void cholsig_kernel(float* __restrict__ Gbuf, float* __restrict__ sigma,
                               const float* __restrict__ tauacc,
                               const float* __restrict__ alphap,
                               const float* __restrict__ lamdap,
                               const float* __restrict__ sigma0,
                               float* __restrict__ rhs, int q) {
    int j = blockIdx.x * TPB + threadIdx.x;
    if (j >= q) return;
    float g[NG];
    #pragma unroll
    for (int k = 0; k < NG; ++k) g[k] = Gbuf[k*q + j];
    #pragma unroll
    for (int a = 0; a < RNK; ++a) {
        #pragma unroll
        for (int b = 0; b < a; ++b) {
            float s = g[tri(a,b)];
            #pragma unroll
            for (int k = 0; k < b; ++k) s -= g[tri(a,k)] * g[tri(b,k)];
            g[tri(a,b)] = s / g[tri(b,b)];
        }
        float s = g[tri(a,a)];
        #pragma unroll
        for (int k = 0; k < a; ++k) s -= g[tri(a,k)] * g[tri(a,k)];
        g[tri(a,a)] = sqrtf(s);
    }
    #pragma unroll
    for (int k = 0; k < NG; ++k) Gbuf[k*q + j] = g[k];
    float nobs = Gbuf[NG*q + j];
    float sg   = *sigma0;
    float tau  = sqrtf(tauacc[j] / (2.0f * nobs * (*alphap))) / sg;
    sigma[j]   = sg * powf(tau, *lamdap);
    #pragma unroll
    for (int k = 0; k < RNK; ++k) rhs[k*q + j] = 0.0f;
}

// pass1 (it=1): sum of (psi*sigma)^2 per regression, 2 columns/thread
__global__ void pass1_kernel(const float* __restrict__ Y, const float* __restrict__ Dm,
                             const float* __restrict__ Bm, const float* __restrict__ sigma,
                             const float* __restrict__ cptr, float* __restrict__ tauacc,
                             int q, int p, int rows) {
    int j0 = 2 * (blockIdx.x * TPB + threadIdx.x);
    int i0 = blockIdx.y * rows, i1 = i0 + rows;
    float b0[RNK], b1[RNK];
    #pragma unroll
    for (int k = 0; k < RNK; ++k) {
        float2 bv = *(const float2*)&Bm[k*q + j0];
        b0[k] = bv.x; b1[k] = bv.y;
    }
    float c = *cptr;
    float csg0 = c * sigma[j0], csg1 = c * sigma[j0+1];
    float a0 = 0.0f, a1 = 0.0f;
    float2 y = *(const float2*)&Y[(size_t)i0*q + j0];
    for (int i = i0; i < i1; ++i) {
        float2 ynxt = (i + 1 < i1) ? *(const float2*)&Y[(size_t)(i+1)*q + j0]
                                   : make_float2(0.0f, 0.0f);
        float dot0 = 0.0f, dot1 = 0.0f;
        #pragma unroll
        for (int k = 0; k < RNK; ++k) {
            float d = Dm[k*p + i];
            dot0 = fmaf(d, b0[k], dot0);
            dot1 = fmaf(d, b1[k], dot1);
        }
        float r0 = (y.x != 0.0f) ? y.x - dot0 : 0.0f;
        float r1 = (y.y != 0.0f) ? y.y - dot1 : 0.0f;
        r0 = fminf(fmaxf(r0, -csg0), csg0);
        r1 = fminf(fmaxf(r1, -csg1), csg1);
        a0 = fmaf(r0, r0, a0);
        a1 = fmaf(r1, r1, a1);
        y = ynxt;
    }
    atomicAdd(&tauacc[j0],   a0);
    atomicAdd(&tauacc[j0+1], a1);
}

// sigma update (it=1): sigma_old = sigma[j]; also zero rhs for next pass2
__global__ void sigma_kernel(const float* __restrict__ tauacc, const float* __restrict__ Gbuf,
                             float* __restrict__ sigma, const float* __restrict__ alphap,
                             const float* __restrict__ lamdap, float* __restrict__ rhs, int q) {
    int j = blockIdx.x * TPB + threadIdx.x;
    if (j >= q) return;
    float nobs = Gbuf[NG*q + j];
    float sg   = sigma[j];
    float tau  = sqrtf(tauacc[j] / (2.0f * nobs * (*alphap))) / sg;
    sigma[j]   = sg * powf(tau, *lamdap);
    #pragma unroll
    for (int k = 0; k < RNK; ++k) rhs[k*q + j] = 0.0f;
}

// pass2: rhs[k][j] += D[i,k] * clamp(resid, +-c*sigma_new), 2 columns/thread
__global__ void pass2_kernel(const float* __restrict__ Y, const float* __restrict__ Dm,
                             const float* __restrict__ Bm, const float* __restrict__ sigma,
                             const float* __restrict__ cptr, float* __restrict__ rhs,
                             int q, int p, int rows) {
    int j0 = 2 * (blockIdx.x * TPB + threadIdx.x);
    int i0 = blockIdx.y * rows, i1 = i0 + rows;
    float b0[RNK], b1[RNK];
    #pragma unroll
    for (int k = 0; k < RNK; ++k) {
        float2 bv = *(const float2*)&Bm[k*q + j0];
        b0[k] = bv.x; b1[k] = bv.y;
    }
    float c = *cptr;
    float csg0 = c * sigma[j0], csg1 = c * sigma[j0+1];
    float a0[RNK], a1[RNK];
    #pragma unroll
    for (int k = 0; k < RNK; ++k) { a0[k] = 0.0f; a1[k] = 0.0f; }
    float2 y = *(const float2*)&Y[(size_t)i0*q + j0];
    for (int i = i0; i < i1; ++i) {
        float2 ynxt = (i + 1 < i1) ? *(const float2*)&Y[(size_t)(i+1)*q + j0]
                                   : make_float2(0.0f, 0.0f);
        float d[RNK];
        #pragma unroll
        for (int k = 0; k < RNK; ++k) d[k] = Dm[k*p + i];
        float dot0 = 0.0f, dot1 = 0.0f;
        #pragma unroll
        for (int k = 0; k < RNK; ++k) {
            dot0 = fmaf(d[k], b0[k], dot0);
            dot1 = fmaf(d[k], b1[k], dot1);
        }
        float r0 = (y.x != 0.0f) ? y.x - dot0 : 0.0f;
        float r1 = (y.y != 0.0f) ? y.y - dot1 : 0.0f;
        r0 = fminf(fmaxf(r0, -csg0), csg0);   // psi2 * sigma
        r1 = fminf(fmaxf(r1, -csg1), csg1);
        #pragma unroll
        for (int k = 0; k < RNK; ++k) {
            a0[k] = fmaf(d[k], r0, a0[k]);
            a1[k] = fmaf(d[k], r1, a1[k]);
        }
        y = ynxt;
    }
    #pragma unroll
    for (int k = 0; k < RNK; ++k) {
        atomicAdd(&rhs[k*q + j0],   a0[k]);
        atomicAdd(&rhs[k*q + j0+1], a1[k]);
    }
}

// solve G delta = rhs via stored Cholesky, beta += mu*delta; zero tauacc (and
// optionally Gbuf, readying the buffers for the next hubreg call).
__global__ void update_kernel(float* __restrict__ Gbuf, const float* __restrict__ rhs,
                              float* __restrict__ Bm, const float* __restrict__ mup,
                              float* __restrict__ tauacc, int q, int zero_g) {
    int j = blockIdx.x * TPB + threadIdx.x;
    if (j >= q) return;
    float L[NG];
    #pragma unroll
    for (int k = 0; k < NG; ++k) L[k] = Gbuf[k*q + j];
    float x[RNK];
    #pragma unroll
    for (int k = 0; k < RNK; ++k) x[k] = rhs[k*q + j];
    #pragma unroll
    for (int a = 0; a < RNK; ++a) {          // forward: L y = rhs
        float s = x[a];
        #pragma unroll
        for (int k = 0; k < a; ++k) s -= L[tri(a,k)] * x[k];
        x[a] = s / L[tri(a,a)];
    }
    #pragma unroll
    for (int a = RNK-1; a >= 0; --a) {       // backward: L^T d = y
        float s = x[a];
        #pragma unroll
        for (int k = a+1; k < RNK; ++k) s -= L[tri(k,a)] * x[k];
        x[a] = s / L[tri(a,a)];
    }
    float mu = *mup;
    #pragma unroll
    for (int k = 0; k < RNK; ++k) Bm[k*q + j] += mu * x[k];
    tauacc[j] = 0.0f;
    if (zero_g) {
        #pragma unroll
        for (int k = 0; k <= NG; ++k) Gbuf[k*q + j] = 0.0f;
    }
}

// final: out[i*n+j] = sum_k Ut[k*m+i] * Vc[k*n+j]
__global__ void gemm_kernel(const float* __restrict__ Ut, const float* __restrict__ Vc,
                            float* __restrict__ out, int m, int n) {
    int j  = blockIdx.x * TPB + threadIdx.x;
    int i0 = blockIdx.y * ITILE;
    float v[RNK];
    #pragma unroll
    for (int k = 0; k < RNK; ++k) v[k] = Vc[k*n + j];
    for (int i = i0; i < i0 + ITILE; ++i) {
        float acc = 0.0f;
        #pragma unroll
        for (int k = 0; k < RNK; ++k) acc = fmaf(Ut[k*m + i], v[k], acc);
        out[(size_t)i*n + j] = acc;
    }
}

// ---------------- host side ----------------

namespace {
struct Scratch {
    float *Ut, *Vc, *Gbuf, *rhs, *sigma, *tauacc, *alpha;
};

static void hubreg(const float* Y, const float* Dm, float* Bm, int q, int p,
                   const float* c, const float* lamda, const float* mu, const float* sigma0,
                   const Scratch& s, hipStream_t stream) {
    dim3 gg(q / TPB, PCH_G);         // fused gram+pass1
    dim3 gp(q / (2 * TPB), PCH_P);   // 2-col pass kernels
    dim3 gj(q / TPB);                // per-regression kernels
    int rg = p / PCH_G, rp = p / PCH_P;

    gp1_kernel    <<<gg, TPB, 0, stream>>>(Y, Dm, Bm, c, sigma0, s.Gbuf, s.tauacc, q, p, rg);
    cholsig_kernel<<<gj, TPB, 0, stream>>>(s.Gbuf, s.sigma, s.tauacc, s.alpha, lamda, sigma0, s.rhs, q);
    pass2_kernel  <<<gp, TPB, 0, stream>>>(Y, Dm, Bm, s.sigma, c, s.rhs, q, p, rp);
    update_kernel <<<gj, TPB, 0, stream>>>(s.Gbuf, s.rhs, Bm, mu, s.tauacc, q, 0);
    pass1_kernel  <<<gp, TPB, 0, stream>>>(Y, Dm, Bm, s.sigma, c, s.tauacc, q, p, rp);
    sigma_kernel  <<<gj, TPB, 0, stream>>>(s.tauacc, s.Gbuf, s.sigma, s.alpha, lamda, s.rhs, q);
    pass2_kernel  <<<gp, TPB, 0, stream>>>(Y, Dm, Bm, s.sigma, c, s.rhs, q, p, rp);
    update_kernel <<<gj, TPB, 0, stream>>>(s.Gbuf, s.rhs, Bm, mu, s.tauacc, q, 1);
}
} // namespace

extern "C" void kernel_launch(void* const* d_in, const int* in_sizes, int n_in,
                              void* d_out, int out_size, void* d_ws, size_t ws_size,
                              hipStream_t stream) {
    const float* Uin    = (const float*)d_in[0];
    const float* Vin    = (const float*)d_in[1];
    const float* X      = (const float*)d_in[2];
    const float* c      = (const float*)d_in[3];
    const float* lamda  = (const float*)d_in[4];
    const float* mu     = (const float*)d_in[5];
    const float* sigma0 = (const float*)d_in[6];
    float* out = (float*)d_out;

    const int m = in_sizes[0] / RNK;   // 4096
    const int n = in_sizes[1] / RNK;   // 4096
    const int qmax = (m > n) ? m : n;

    float* w = (float*)d_ws;
    auto align64 = [](size_t x) { return (x + 63) & ~(size_t)63; };
    size_t off = 0;
    Scratch s;
    s.Ut     = w + off; off = align64(off + (size_t)RNK * m);
    s.Vc     = w + off; off = align64(off + (size_t)RNK * n);
    s.Gbuf   = w + off; off = align64(off + (size_t)(NG + 1) * qmax);
    s.rhs    = w + off; off = align64(off + (size_t)RNK * qmax);
    s.sigma  = w + off; off = align64(off + (size_t)qmax);
    s.tauacc = w + off; off = align64(off + (size_t)qmax);
    s.alpha  = w + off; off = align64(off + 64);
    (void)ws_size; (void)n_in; (void)out_size;

    {
        int tot = (NG + 1) * qmax;
        init_kernel<<<(tot + TPB - 1) / TPB, TPB, 0, stream>>>(
            Uin, Vin, c, s.Ut, s.Vc, s.Gbuf, s.tauacc, s.alpha, m, n, qmax);
    }
    // X [m,n] -> XT [n,m] staged in d_out (dead until final GEMM overwrites it)
    transpose_kernel<<<dim3(n / 32, m / 32), dim3(32, 8), 0, stream>>>(X, out, m, n);

    for (int layer = 0; layer < 3; ++layer) {
        // V-step: q=n regressions (columns of X), D = U rows, beta = V cols
        hubreg(X,   s.Ut, s.Vc, n, m, c, lamda, mu, sigma0, s, stream);
        // U-step: q=m regressions (rows of X), Y = XT, D = V cols, beta = U rows
        hubreg(out, s.Vc, s.Ut, m, n, c, lamda, mu, sigma0, s, stream);
    }

    gemm_kernel<<<dim3(n / TPB, m / ITILE), TPB, 0, stream>>>(s.Ut, s.Vc, out, m, n);
}

// Round 3
// 1468.653 us; speedup vs baseline: 1.2643x; 1.1164x over previous
//
#include <hip/hip_runtime.h>
#include <math.h>

#define RNK 10
#define NG  55          // packed lower-triangular 10x10
#define TPB 256
#define PCH_G 64        // row-chunks for fused gram+pass1 (grid.y); rows=64
#define PCH_P 128       // row-chunks for pass1/pass2 (grid.y); rows=32
#define ITILE 16        // rows per block in final GEMM

__device__ __forceinline__ constexpr int tri(int a, int b) { return a*(a+1)/2 + b; }

// ---------------- init ----------------
__global__ void init_kernel(const float* __restrict__ Uin, const float* __restrict__ Vin,
                            const float* __restrict__ cptr,
                            float* __restrict__ Ut, float* __restrict__ Vc,
                            float* __restrict__ Gbuf, float* __restrict__ tauacc,
                            float* __restrict__ alpha, int m, int n, int qmax) {
    int idx = blockIdx.x * TPB + threadIdx.x;
    if (idx == 0) {
        float c  = *cptr;
        float A  = erff(c * 0.70710678118654752f);              // chi2_cdf(c^2, 1)
        float B  = c * 0.79788456080286536f * expf(-0.5f*c*c);
        *alpha = 0.5f*c*c*(1.0f - A) + 0.5f*(A - B);            // chi2_cdf(c^2,3)=A-B
    }
    if (idx < RNK * m) { int k = idx / m, i = idx - k*m; Ut[idx] = Uin[i*RNK + k]; }
    if (idx < RNK * n) Vc[idx] = Vin[idx];
    if (idx < (NG + 1) * qmax) Gbuf[idx] = 0.0f;
    if (idx < qmax) tauacc[idx] = 0.0f;
}

// X [m,n] -> XT [n,m], 32x32 LDS tile
__global__ void transpose_kernel(const float* __restrict__ X, float* __restrict__ XT,
                                 int m, int n) {
    __shared__ float tile[32][33];
    int bx = blockIdx.x * 32, by = blockIdx.y * 32;
    int tx = threadIdx.x, ty = threadIdx.y;  // block (32,8)
    #pragma unroll
    for (int dy = 0; dy < 32; dy += 8)
        tile[ty+dy][tx] = X[(size_t)(by+ty+dy)*n + bx + tx];
    __syncthreads();
    #pragma unroll
    for (int dy = 0; dy < 32; dy += 8)
        XT[(size_t)(bx+ty+dy)*m + by + tx] = tile[tx][ty+dy];
}

// ---------------- hubreg kernels ----------------
// Layouts: Y [p,q] (regression j fast axis), Dm [r,p] (wave-uniform rows),
//          Bm [r,q] (coalesced per-thread beta).

// Fused Gram + pass1(it=0). i-loop unrolled x4 with grouped prefetch: 4-8
// independent Y loads in flight per wave (latency was the round-2 stall).
__global__ void gp1_kernel(const float* __restrict__ Y, const float* __restrict__ Dm,
                           const float* __restrict__ Bm, const float* __restrict__ cptr,
                           const float* __restrict__ sigma0,
                           float* __restrict__ Gbuf, float* __restrict__ tauacc,
                           int q, int p, int rows) {
    int j  = blockIdx.x * TPB + threadIdx.x;
    int i0 = blockIdx.y * rows, i1 = i0 + rows;   // rows % 4 == 0
    float b[RNK];
    #pragma unroll
    for (int k = 0; k < RNK; ++k) b[k] = Bm[k*q + j];
    float csg = (*cptr) * (*sigma0);
    float acc[NG];
    #pragma unroll
    for (int k = 0; k < NG; ++k) acc[k] = 0.0f;
    float cnt = 0.0f, p1 = 0.0f;
    float y[4];
    #pragma unroll
    for (int u = 0; u < 4; ++u) y[u] = Y[(size_t)(i0+u)*q + j];
    for (int i = i0; i < i1; i += 4) {
        float yn[4];
        if (i + 4 < i1) {
            #pragma unroll
            for (int u = 0; u < 4; ++u) yn[u] = Y[(size_t)(i+4+u)*q + j];
        } else {
            #pragma unroll
            for (int u = 0; u < 4; ++u) yn[u] = 0.0f;
        }
        #pragma unroll
        for (int u = 0; u < 4; ++u) {
            int row = i + u;
            float d[RNK];
            #pragma unroll
            for (int k = 0; k < RNK; ++k) d[k] = Dm[k*p + row];
            float yv  = y[u];
            float msk = (yv != 0.0f) ? 1.0f : 0.0f;
            cnt += msk;
            float dot = 0.0f;
            #pragma unroll
            for (int k = 0; k < RNK; ++k) dot = fmaf(d[k], b[k], dot);
            float r = (yv != 0.0f) ? yv - dot : 0.0f;
            r = fminf(fmaxf(r, -csg), csg);          // psi(R/sig0)*sig0
            p1 = fmaf(r, r, p1);
            float dm[RNK];
            #pragma unroll
            for (int k = 0; k < RNK; ++k) dm[k] = msk * d[k];
            #pragma unroll
            for (int a = 0; a < RNK; ++a)
                #pragma unroll
                for (int bb = 0; bb <= a; ++bb)
                    acc[tri(a,bb)] = fmaf(dm[a], d[bb], acc[tri(a,bb)]);
        }
        #pragma unroll
        for (int u = 0; u < 4; ++u) y[u] = yn[u];
    }
    #pragma unroll
    for (int k = 0; k < NG; ++k) atomicAdd(&Gbuf[k*q + j], acc[k]);
    atomicAdd(&Gbuf[NG*q + j], cnt);
    atomicAdd(&tauacc[j], p1);
}

// Fused Cholesky + sigma-update (it=0, sigma_old = sigma0) + rhs zeroing
__global__ void cholsig_kernel(float* __restrict__ Gbuf, float* __restrict__ sigma,
                               const float* __restrict__ tauacc,
                               const float* __restrict__ alphap,
                               const float* __restrict__ lamdap,
                               const float* __restrict__ sigma0,
                               float* __restrict__ rhs, int q) {
    int j = blockIdx.x * TPB + threadIdx.x;
    if (j >= q) return;
    float g[NG];
    #pragma unroll
    for (int k = 0; k < NG; ++k) g[k] = Gbuf[k*q + j];
    #pragma unroll
    for (int a = 0; a < RNK; ++a) {
        #pragma unroll
        for (int b = 0; b < a; ++b) {
            float s = g[tri(a,b)];
            #pragma unroll
            for (int k = 0; k < b; ++k) s -= g[tri(a,k)] * g[tri(b,k)];
            g[tri(a,b)] = s / g[tri(b,b)];
        }
        float s = g[tri(a,a)];
        #pragma unroll
        for (int k = 0; k < a; ++k) s -= g[tri(a,k)] * g[tri(a,k)];
        g[tri(a,a)] = sqrtf(s);
    }
    #pragma unroll
    for (int k = 0; k < NG; ++k) Gbuf[k*q + j] = g[k];
    float nobs = Gbuf[NG*q + j];
    float sg   = *sigma0;
    float tau  = sqrtf(tauacc[j] / (2.0f * nobs * (*alphap))) / sg;
    sigma[j]   = sg * powf(tau, *lamdap);
    #pragma unroll
    for (int k = 0; k < RNK; ++k) rhs[k*q + j] = 0.0f;
}

// pass1 (it=1): sum of (psi*sigma)^2 per regression; 4 rows x 2 cols per iter
__global__ void pass1_kernel(const float* __restrict__ Y, const float* __restrict__ Dm,
                             const float* __restrict__ Bm, const float* __restrict__ sigma,
                             const float* __restrict__ cptr, float* __restrict__ tauacc,
                             int q, int p, int rows) {
    int j0 = 2 * (blockIdx.x * TPB + threadIdx.x);
    int i0 = blockIdx.y * rows, i1 = i0 + rows;   // rows % 4 == 0
    float b0[RNK], b1[RNK];
    #pragma unroll
    for (int k = 0; k < RNK; ++k) {
        float2 bv = *(const float2*)&Bm[k*q + j0];
        b0[k] = bv.x; b1[k] = bv.y;
    }
    float c = *cptr;
    float csg0 = c * sigma[j0], csg1 = c * sigma[j0+1];
    float a0 = 0.0f, a1 = 0.0f;
    float2 y[4];
    #pragma unroll
    for (int u = 0; u < 4; ++u) y[u] = *(const float2*)&Y[(size_t)(i0+u)*q + j0];
    for (int i = i0; i < i1; i += 4) {
        float2 yn[4];
        if (i + 4 < i1) {
            #pragma unroll
            for (int u = 0; u < 4; ++u) yn[u] = *(const float2*)&Y[(size_t)(i+4+u)*q + j0];
        } else {
            #pragma unroll
            for (int u = 0; u < 4; ++u) yn[u] = make_float2(0.0f, 0.0f);
        }
        #pragma unroll
        for (int u = 0; u < 4; ++u) {
            int row = i + u;
            float dot0 = 0.0f, dot1 = 0.0f;
            #pragma unroll
            for (int k = 0; k < RNK; ++k) {
                float d = Dm[k*p + row];
                dot0 = fmaf(d, b0[k], dot0);
                dot1 = fmaf(d, b1[k], dot1);
            }
            float r0 = (y[u].x != 0.0f) ? y[u].x - dot0 : 0.0f;
            float r1 = (y[u].y != 0.0f) ? y[u].y - dot1 : 0.0f;
            r0 = fminf(fmaxf(r0, -csg0), csg0);
            r1 = fminf(fmaxf(r1, -csg1), csg1);
            a0 = fmaf(r0, r0, a0);
            a1 = fmaf(r1, r1, a1);
        }
        #pragma unroll
        for (int u = 0; u < 4; ++u) y[u] = yn[u];
    }
    atomicAdd(&tauacc[j0],   a0);
    atomicAdd(&tauacc[j0+1], a1);
}

// sigma update (it=1): sigma_old = sigma[j]; also zero rhs for next pass2
__global__ void sigma_kernel(const float* __restrict__ tauacc, const float* __restrict__ Gbuf,
                             float* __restrict__ sigma, const float* __restrict__ alphap,
                             const float* __restrict__ lamdap, float* __restrict__ rhs, int q) {
    int j = blockIdx.x * TPB + threadIdx.x;
    if (j >= q) return;
    float nobs = Gbuf[NG*q + j];
    float sg   = sigma[j];
    float tau  = sqrtf(tauacc[j] / (2.0f * nobs * (*alphap))) / sg;
    sigma[j]   = sg * powf(tau, *lamdap);
    #pragma unroll
    for (int k = 0; k < RNK; ++k) rhs[k*q + j] = 0.0f;
}

// pass2: rhs[k][j] += D[i,k] * clamp(resid, +-c*sigma); 4 rows x 2 cols per iter
__global__ void pass2_kernel(const float* __restrict__ Y, const float* __restrict__ Dm,
                             const float* __restrict__ Bm, const float* __restrict__ sigma,
                             const float* __restrict__ cptr, float* __restrict__ rhs,
                             int q, int p, int rows) {
    int j0 = 2 * (blockIdx.x * TPB + threadIdx.x);
    int i0 = blockIdx.y * rows, i1 = i0 + rows;
    float b0[RNK], b1[RNK];
    #pragma unroll
    for (int k = 0; k < RNK; ++k) {
        float2 bv = *(const float2*)&Bm[k*q + j0];
        b0[k] = bv.x; b1[k] = bv.y;
    }
    float c = *cptr;
    float csg0 = c * sigma[j0], csg1 = c * sigma[j0+1];
    float a0[RNK], a1[RNK];
    #pragma unroll
    for (int k = 0; k < RNK; ++k) { a0[k] = 0.0f; a1[k] = 0.0f; }
    float2 y[4];
    #pragma unroll
    for (int u = 0; u < 4; ++u) y[u] = *(const float2*)&Y[(size_t)(i0+u)*q + j0];
    for (int i = i0; i < i1; i += 4) {
        float2 yn[4];
        if (i + 4 < i1) {
            #pragma unroll
            for (int u = 0; u < 4; ++u) yn[u] = *(const float2*)&Y[(size_t)(i+4+u)*q + j0];
        } else {
            #pragma unroll
            for (int u = 0; u < 4; ++u) yn[u] = make_float2(0.0f, 0.0f);
        }
        #pragma unroll
        for (int u = 0; u < 4; ++u) {
            int row = i + u;
            float d[RNK];
            #pragma unroll
            for (int k = 0; k < RNK; ++k) d[k] = Dm[k*p + row];
            float dot0 = 0.0f, dot1 = 0.0f;
            #pragma unroll
            for (int k = 0; k < RNK; ++k) {
                dot0 = fmaf(d[k], b0[k], dot0);
                dot1 = fmaf(d[k], b1[k], dot1);
            }
            float r0 = (y[u].x != 0.0f) ? y[u].x - dot0 : 0.0f;
            float r1 = (y[u].y != 0.0f) ? y[u].y - dot1 : 0.0f;
            r0 = fminf(fmaxf(r0, -csg0), csg0);   // psi2 * sigma
            r1 = fminf(fmaxf(r1, -csg1), csg1);
            #pragma unroll
            for (int k = 0; k < RNK; ++k) {
                a0[k] = fmaf(d[k], r0, a0[k]);
                a1[k] = fmaf(d[k], r1, a1[k]);
            }
        }
        #pragma unroll
        for (int u = 0; u < 4; ++u) y[u] = yn[u];
    }
    #pragma unroll
    for (int k = 0; k < RNK; ++k) {
        atomicAdd(&rhs[k*q + j0],   a0[k]);
        atomicAdd(&rhs[k*q + j0+1], a1[k]);
    }
}

// solve G delta = rhs via stored Cholesky, beta += mu*delta; zero tauacc (and
// optionally Gbuf for the next hubreg call).
__global__ void update_kernel(float* __restrict__ Gbuf, const float* __restrict__ rhs,
                              float* __restrict__ Bm, const float* __restrict__ mup,
                              float* __restrict__ tauacc, int q, int zero_g) {
    int j = blockIdx.x * TPB + threadIdx.x;
    if (j >= q) return;
    float L[NG];
    #pragma unroll
    for (int k = 0; k < NG; ++k) L[k] = Gbuf[k*q + j];
    float x[RNK];
    #pragma unroll
    for (int k = 0; k < RNK; ++k) x[k] = rhs[k*q + j];
    #pragma unroll
    for (int a = 0; a < RNK; ++a) {          // forward: L y = rhs
        float s = x[a];
        #pragma unroll
        for (int k = 0; k < a; ++k) s -= L[tri(a,k)] * x[k];
        x[a] = s / L[tri(a,a)];
    }
    #pragma unroll
    for (int a = RNK-1; a >= 0; --a) {       // backward: L^T d = y
        float s = x[a];
        #pragma unroll
        for (int k = a+1; k < RNK; ++k) s -= L[tri(k,a)] * x[k];
        x[a] = s / L[tri(a,a)];
    }
    float mu = *mup;
    #pragma unroll
    for (int k = 0; k < RNK; ++k) Bm[k*q + j] += mu * x[k];
    tauacc[j] = 0.0f;
    if (zero_g) {
        #pragma unroll
        for (int k = 0; k <= NG; ++k) Gbuf[k*q + j] = 0.0f;
    }
}

// final: out[i*n+j] = sum_k Ut[k*m+i] * Vc[k*n+j]
__global__ void gemm_kernel(const float* __restrict__ Ut, const float* __restrict__ Vc,
                            float* __restrict__ out, int m, int n) {
    int j  = blockIdx.x * TPB + threadIdx.x;
    int i0 = blockIdx.y * ITILE;
    float v[RNK];
    #pragma unroll
    for (int k = 0; k < RNK; ++k) v[k] = Vc[k*n + j];
    for (int i = i0; i < i0 + ITILE; ++i) {
        float acc = 0.0f;
        #pragma unroll
        for (int k = 0; k < RNK; ++k) acc = fmaf(Ut[k*m + i], v[k], acc);
        out[(size_t)i*n + j] = acc;
    }
}

// ---------------- host side ----------------

namespace {
struct Scratch {
    float *Ut, *Vc, *Gbuf, *rhs, *sigma, *tauacc, *alpha;
};

static void hubreg(const float* Y, const float* Dm, float* Bm, int q, int p,
                   const float* c, const float* lamda, const float* mu, const float* sigma0,
                   const Scratch& s, hipStream_t stream) {
    dim3 gg(q / TPB, PCH_G);         // fused gram+pass1
    dim3 gp(q / (2 * TPB), PCH_P);   // 2-col pass kernels
    dim3 gj(q / TPB);                // per-regression kernels
    int rg = p / PCH_G, rp = p / PCH_P;

    gp1_kernel    <<<gg, TPB, 0, stream>>>(Y, Dm, Bm, c, sigma0, s.Gbuf, s.tauacc, q, p, rg);
    cholsig_kernel<<<gj, TPB, 0, stream>>>(s.Gbuf, s.sigma, s.tauacc, s.alpha, lamda, sigma0, s.rhs, q);
    pass2_kernel  <<<gp, TPB, 0, stream>>>(Y, Dm, Bm, s.sigma, c, s.rhs, q, p, rp);
    update_kernel <<<gj, TPB, 0, stream>>>(s.Gbuf, s.rhs, Bm, mu, s.tauacc, q, 0);
    pass1_kernel  <<<gp, TPB, 0, stream>>>(Y, Dm, Bm, s.sigma, c, s.tauacc, q, p, rp);
    sigma_kernel  <<<gj, TPB, 0, stream>>>(s.tauacc, s.Gbuf, s.sigma, s.alpha, lamda, s.rhs, q);
    pass2_kernel  <<<gp, TPB, 0, stream>>>(Y, Dm, Bm, s.sigma, c, s.rhs, q, p, rp);
    update_kernel <<<gj, TPB, 0, stream>>>(s.Gbuf, s.rhs, Bm, mu, s.tauacc, q, 1);
}
} // namespace

extern "C" void kernel_launch(void* const* d_in, const int* in_sizes, int n_in,
                              void* d_out, int out_size, void* d_ws, size_t ws_size,
                              hipStream_t stream) {
    const float* Uin    = (const float*)d_in[0];
    const float* Vin    = (const float*)d_in[1];
    const float* X      = (const float*)d_in[2];
    const float* c      = (const float*)d_in[3];
    const float* lamda  = (const float*)d_in[4];
    const float* mu     = (const float*)d_in[5];
    const float* sigma0 = (const float*)d_in[6];
    float* out = (float*)d_out;

    const int m = in_sizes[0] / RNK;   // 4096
    const int n = in_sizes[1] / RNK;   // 4096
    const int qmax = (m > n) ? m : n;

    float* w = (float*)d_ws;
    auto align64 = [](size_t x) { return (x + 63) & ~(size_t)63; };
    size_t off = 0;
    Scratch s;
    s.Ut     = w + off; off = align64(off + (size_t)RNK * m);
    s.Vc     = w + off; off = align64(off + (size_t)RNK * n);
    s.Gbuf   = w + off; off = align64(off + (size_t)(NG + 1) * qmax);
    s.rhs    = w + off; off = align64(off + (size_t)RNK * qmax);
    s.sigma  = w + off; off = align64(off + (size_t)qmax);
    s.tauacc = w + off; off = align64(off + (size_t)qmax);
    s.alpha  = w + off; off = align64(off + 64);
    (void)ws_size; (void)n_in; (void)out_size;

    {
        int tot = (NG + 1) * qmax;
        init_kernel<<<(tot + TPB - 1) / TPB, TPB, 0, stream>>>(
            Uin, Vin, c, s.Ut, s.Vc, s.Gbuf, s.tauacc, s.alpha, m, n, qmax);
    }
    // X [m,n] -> XT [n,m] staged in d_out (dead until final GEMM overwrites it)
    transpose_kernel<<<dim3(n / 32, m / 32), dim3(32, 8), 0, stream>>>(X, out, m, n);

    for (int layer = 0; layer < 3; ++layer) {
        // V-step: q=n regressions (columns of X), D = U rows, beta = V cols
        hubreg(X,   s.Ut, s.Vc, n, m, c, lamda, mu, sigma0, s, stream);
        // U-step: q=m regressions (rows of X), Y = XT, D = V cols, beta = U rows
        hubreg(out, s.Vc, s.Ut, m, n, c, lamda, mu, sigma0, s, stream);
    }

    gemm_kernel<<<dim3(n / TPB, m / ITILE), TPB, 0, stream>>>(s.Ut, s.Vc, out, m, n);
}